// Round 7
// baseline (139.170 us; speedup 1.0000x reference)
//
#include <hip/hip_runtime.h>
#include <math.h>

// Problem constants
#define Bsz 64
#define IC  512   // in_caps
#define KD  128   // in_dim
#define NC  32    // num_caps
#define DC  32    // dim_caps
#define CHUNK 64  // in_caps per block
#define NCH   8   // IC / CHUNK
#define NBLK  512 // Bsz * NCH
#define NTHR  256

#define CSTR 36   // padded stride for c_sT / wv_sT rows (floats)
#define BSTR 68   // padded stride for bb_s rows
#define WSTR 33   // padded stride for w_s rows: bank=(k+d)%32 -> conflict-free col+row reads

// workspace layout (floats)
#define CXP_SZ (Bsz * NCH * NC * KD)   // 8 MB   cx partials [b][ch][n][k]
#define WV_SZ  (Bsz * NC * KD)         // 1 MB   wv [b][n][k]

// x_s storage: row i holds k-quads rotated by (i>>2): quad' = (quad + (i>>2)) & 31
__device__ __forceinline__ int xaddr(int i, int kq) {
    return i * KD + ((((kq) + (i >> 2)) & 31) << 2);
}

// ---------------- Kernel A: [uv + bb update] + softmax + cx partials ----------------
// r3 base. DS-pipe-bound phases re-tiled for fewer wave-level ds_read_b128:
//   uv: t<64, 4n x 8i  (12 reads / 128 MAC per kq;   384 vs 512 wave-instr/block)
//   cx: t<128, 4n x 8k (3 reads / 32 MAC per ii;     384 vs 512 wave-instr/block)
// Idle threads are free: the DS pipe is per-CU and is the binding resource.
__global__ __launch_bounds__(NTHR)
void kA(const float* __restrict__ bb_in, const float* __restrict__ x_g,
        const float* __restrict__ wv_g, float* __restrict__ bb_out,
        float* __restrict__ cxp, int do_uv, int write_bb)
{
    __shared__ float x_s[CHUNK * KD];      // 32 KB, quad-rotated
    __shared__ float bb_s[NC * BSTR];      // 8.5 KB
    __shared__ float scr[KD * CSTR];       // 18 KB union: wv_sT [k][n] then c_sT [i][n]

    const int t = threadIdx.x, blk = blockIdx.x;
    const int b = blk >> 3, ch = blk & 7, i0g = ch * CHUNK;

    // stage x (rotated)
    for (int rep = 0; rep < 8; ++rep) {
        int v = t + rep * NTHR;            // float4 idx 0..2047
        int i = v >> 5, kq = v & 31;
        *(float4*)(x_s + xaddr(i, kq)) =
            *(const float4*)(x_g + ((size_t)(b * IC + i0g + i)) * KD + (kq << 2));
    }
    // stage bb
    for (int rep = 0; rep < 2; ++rep) {
        int v = t + rep * NTHR;            // 0..511
        int n = v >> 4, i4 = v & 15;
        *(float4*)(bb_s + n * BSTR + (i4 << 2)) =
            *(const float4*)(bb_in + ((size_t)(b * NC + n)) * IC + i0g + (i4 << 2));
    }
    if (do_uv) {
        // stage wv transposed: [k][n] with CSTR pad
        for (int rep = 0; rep < 4; ++rep) {
            const int n = t & 31;
            const int k4 = (t >> 5) + (rep << 3);   // 0..31
            float4 v4 = *(const float4*)(wv_g + ((size_t)(b * NC) + n) * KD + (k4 << 2));
            scr[(k4 * 4 + 0) * CSTR + n] = v4.x;
            scr[(k4 * 4 + 1) * CSTR + n] = v4.y;
            scr[(k4 * 4 + 2) * CSTR + n] = v4.z;
            scr[(k4 * 4 + 3) * CSTR + n] = v4.w;
        }
    }
    __syncthreads();

    if (do_uv) {
        // uv = wv @ X^T ; bb += uv. t<64: 4n x 8i tile; w-quads reused across 8 i-rows.
        if (t < 64) {
            const int tn = t & 7, ti = t >> 3;
            const int n0 = tn << 2, i0 = ti << 3;
            float4 a[8];
            #pragma unroll
            for (int r = 0; r < 8; ++r) a[r] = (float4){0,0,0,0};
            for (int kq = 0; kq < 32; ++kq) {
                const float4 w0 = *(const float4*)(scr + (kq * 4 + 0) * CSTR + n0);
                const float4 w1 = *(const float4*)(scr + (kq * 4 + 1) * CSTR + n0);
                const float4 w2 = *(const float4*)(scr + (kq * 4 + 2) * CSTR + n0);
                const float4 w3 = *(const float4*)(scr + (kq * 4 + 3) * CSTR + n0);
                #pragma unroll
                for (int r = 0; r < 8; ++r) {
                    const float4 xr = *(const float4*)(x_s + xaddr(i0 + r, kq));
                    a[r].x += xr.x*w0.x + xr.y*w1.x + xr.z*w2.x + xr.w*w3.x;
                    a[r].y += xr.x*w0.y + xr.y*w1.y + xr.z*w2.y + xr.w*w3.y;
                    a[r].z += xr.x*w0.z + xr.y*w1.z + xr.z*w2.z + xr.w*w3.z;
                    a[r].w += xr.x*w0.w + xr.y*w1.w + xr.z*w2.w + xr.w*w3.w;
                }
            }
            #pragma unroll
            for (int r = 0; r < 8; ++r) {
                bb_s[(n0+0)*BSTR + i0 + r] += a[r].x;
                bb_s[(n0+1)*BSTR + i0 + r] += a[r].y;
                bb_s[(n0+2)*BSTR + i0 + r] += a[r].z;
                bb_s[(n0+3)*BSTR + i0 + r] += a[r].w;
            }
        }
        __syncthreads();
        if (write_bb) {
            for (int rep = 0; rep < 2; ++rep) {
                int v = t + rep * NTHR;
                int n = v >> 4, i4 = v & 15;
                *(float4*)(bb_out + ((size_t)(b * NC + n)) * IC + i0g + (i4 << 2)) =
                    *(const float4*)(bb_s + n * BSTR + (i4 << 2));
            }
        }
    }

    // softmax over n for each ii (t<64 serial form, r0/r3-proven; conflict-free column reads)
    if (t < CHUNK) {
        const int ii = t;
        float m = -1e30f;
        #pragma unroll
        for (int n = 0; n < NC; ++n) m = fmaxf(m, bb_s[n * BSTR + ii]);
        float e[NC]; float sum = 0.f;
        #pragma unroll
        for (int n = 0; n < NC; ++n) { float ev = __expf(bb_s[n * BSTR + ii] - m); e[n] = ev; sum += ev; }
        const float inv = 1.f / sum;
        float* crow = scr + ii * CSTR;
        #pragma unroll
        for (int n = 0; n < NC; ++n) crow[n] = e[n] * inv;
    }
    __syncthreads();

    // cx = C @ X (32n x 128k over 64 i); t<128: 4n x 8k per thread (3 reads / 32 MAC / ii)
    if (t < 128) {
        const int tn = t & 7, tkp = t >> 3;     // tkp 0..15: k-quad pair
        const int n0 = tn << 2, kq0 = tkp << 1;
        float4 aA0={0,0,0,0}, aA1={0,0,0,0}, aA2={0,0,0,0}, aA3={0,0,0,0};
        float4 aB0={0,0,0,0}, aB1={0,0,0,0}, aB2={0,0,0,0}, aB3={0,0,0,0};
        for (int ii = 0; ii < CHUNK; ++ii) {
            const float4 c4 = *(const float4*)(scr + ii * CSTR + n0);
            const float4 xA = *(const float4*)(x_s + xaddr(ii, kq0));
            const float4 xB = *(const float4*)(x_s + xaddr(ii, kq0 + 1));
            aA0.x += c4.x*xA.x; aA0.y += c4.x*xA.y; aA0.z += c4.x*xA.z; aA0.w += c4.x*xA.w;
            aB0.x += c4.x*xB.x; aB0.y += c4.x*xB.y; aB0.z += c4.x*xB.z; aB0.w += c4.x*xB.w;
            aA1.x += c4.y*xA.x; aA1.y += c4.y*xA.y; aA1.z += c4.y*xA.z; aA1.w += c4.y*xA.w;
            aB1.x += c4.y*xB.x; aB1.y += c4.y*xB.y; aB1.z += c4.y*xB.z; aB1.w += c4.y*xB.w;
            aA2.x += c4.z*xA.x; aA2.y += c4.z*xA.y; aA2.z += c4.z*xA.z; aA2.w += c4.z*xA.w;
            aB2.x += c4.z*xB.x; aB2.y += c4.z*xB.y; aB2.z += c4.z*xB.z; aB2.w += c4.z*xB.w;
            aA3.x += c4.w*xA.x; aA3.y += c4.w*xA.y; aA3.z += c4.w*xA.z; aA3.w += c4.w*xA.w;
            aB3.x += c4.w*xB.x; aB3.y += c4.w*xB.y; aB3.z += c4.w*xB.z; aB3.w += c4.w*xB.w;
        }
        float* base = cxp + ((size_t)(b * NCH + ch)) * NC * KD + (kq0 << 2);
        float* p0 = base + (size_t)(n0 + 0) * KD;
        float* p1 = base + (size_t)(n0 + 1) * KD;
        float* p2 = base + (size_t)(n0 + 2) * KD;
        float* p3 = base + (size_t)(n0 + 3) * KD;
        *(float4*)(p0) = aA0; *(float4*)(p0 + 4) = aB0;
        *(float4*)(p1) = aA1; *(float4*)(p1 + 4) = aB1;
        *(float4*)(p2) = aA2; *(float4*)(p2 + 4) = aB2;
        *(float4*)(p3) = aA3; *(float4*)(p3 + 4) = aB3;
    }
}

// ---------------- Kernel B: reduce partials, s = cx@W[n], squash, wv or out ----------------
// (r3 structure, verified)
__global__ __launch_bounds__(NTHR)
void kB(const float* __restrict__ cxp, const float* __restrict__ W_g,
        float* __restrict__ wv_g, float* __restrict__ out_g, int final_)
{
    __shared__ float w_s[KD * WSTR];       // 16.5 KB, padded [k][d], bank=(k+d)%32
    __shared__ float cxs[4 * KD];          // 2 KB: per-wave reduced cx row
    __shared__ float vb[4 * DC];           // 512 B: per-wave squashed v

    const int t = threadIdx.x, blk = blockIdx.x;
    const int pb_n = blk & 31, pb_b0 = (blk >> 5) * 4;
    const int w = t >> 6, l = t & 63;
    const int b = pb_b0 + w;

    for (int rep = 0; rep < 4; ++rep) {
        int v = t + rep * NTHR;            // 0..1023 float4s
        int k = v >> 3, d0 = (v & 7) << 2;
        float4 w4 = *(const float4*)(W_g + (size_t)pb_n * KD * DC + ((size_t)v << 2));
        float* dst = w_s + k * WSTR + d0;
        dst[0] = w4.x; dst[1] = w4.y; dst[2] = w4.z; dst[3] = w4.w;
    }
    {
        float c0 = 0.f, c1 = 0.f;
        const float* p = cxp + ((size_t)b * NCH * NC + pb_n) * KD;
        #pragma unroll
        for (int c2 = 0; c2 < NCH; ++c2) {
            c0 += p[(size_t)c2 * NC * KD + l];
            c1 += p[(size_t)c2 * NC * KD + l + 64];
        }
        cxs[w * KD + l] = c0; cxs[w * KD + l + 64] = c1;
    }
    __syncthreads();

    const int dgrp = l & 7, d0 = dgrp << 2, kg = l >> 3;
    const float* cxw = cxs + w * KD;
    float4 acc = {0,0,0,0};
    #pragma unroll
    for (int j = 0; j < 16; ++j) {
        const int k = (j << 3) + kg;
        const float* wr = w_s + k * WSTR + d0;
        const float cv = cxw[k];
        acc.x += cv * wr[0]; acc.y += cv * wr[1]; acc.z += cv * wr[2]; acc.w += cv * wr[3];
    }
    #pragma unroll
    for (int off = 8; off < 64; off <<= 1) {
        acc.x += __shfl_xor(acc.x, off, 64);
        acc.y += __shfl_xor(acc.y, off, 64);
        acc.z += __shfl_xor(acc.z, off, 64);
        acc.w += __shfl_xor(acc.w, off, 64);
    }
    float ss = acc.x*acc.x + acc.y*acc.y + acc.z*acc.z + acc.w*acc.w;
    #pragma unroll
    for (int off = 1; off < 8; off <<= 1) ss += __shfl_xor(ss, off, 64);
    const float scale = ss / ((1.f + ss) * (sqrtf(ss) + 1e-8f));
    float4 v4; v4.x = acc.x*scale; v4.y = acc.y*scale; v4.z = acc.z*scale; v4.w = acc.w*scale;

    if (final_) {
        if (kg == 0) *(float4*)(out_g + ((size_t)(b * NC) + pb_n) * DC + d0) = v4;
    } else {
        float* vbw = vb + w * DC;
        if (kg == 0) *(float4*)(vbw + d0) = v4;
        __syncthreads();
        float wv0 = 0.f, wv1 = 0.f;
        #pragma unroll
        for (int j = 0; j < 8; ++j) {
            const float4 vv = *(const float4*)(vbw + (j << 2));
            const float* wa = w_s + l * WSTR + (j << 2);
            const float* wb = w_s + (l + 64) * WSTR + (j << 2);
            wv0 += wa[0]*vv.x + wa[1]*vv.y + wa[2]*vv.z + wa[3]*vv.w;
            wv1 += wb[0]*vv.x + wb[1]*vv.y + wb[2]*vv.z + wb[3]*vv.w;
        }
        float* wrow = wv_g + ((size_t)(b * NC) + pb_n) * KD;
        wrow[l] = wv0; wrow[l + 64] = wv1;
    }
}

extern "C" void kernel_launch(void* const* d_in, const int* in_sizes, int n_in,
                              void* d_out, int out_size, void* d_ws, size_t ws_size,
                              hipStream_t stream) {
    const float* x  = (const float*)d_in[0];
    const float* W  = (const float*)d_in[1];
    const float* b0 = (const float*)d_in[2];
    float* out = (float*)d_out;

    float* cxp   = (float*)d_ws;                 // 8 MB
    float* wv    = cxp + CXP_SZ;                 // 1 MB
    float* bb_ws = wv + WV_SZ;                   // 4 MB

    // iter 0: softmax(b0) + cx
    kA<<<NBLK, NTHR, 0, stream>>>(b0, x, nullptr, nullptr, cxp, 0, 0);
    kB<<<NBLK, NTHR, 0, stream>>>(cxp, W, wv, nullptr, 0);
    // iter 1: uv+bb (persist) + softmax + cx
    kA<<<NBLK, NTHR, 0, stream>>>(b0, x, wv, bb_ws, cxp, 1, 1);
    kB<<<NBLK, NTHR, 0, stream>>>(cxp, W, wv, nullptr, 0);
    // iter 2: uv+bb + softmax + cx (bb not persisted)
    kA<<<NBLK, NTHR, 0, stream>>>(bb_ws, x, wv, nullptr, cxp, 1, 0);
    kB<<<NBLK, NTHR, 0, stream>>>(cxp, W, nullptr, out, 1);
}

// Round 8
// 127.427 us; speedup vs baseline: 1.0921x; 1.0921x over previous
//
#include <hip/hip_runtime.h>
#include <math.h>

// Problem constants
#define Bsz 64
#define IC  512   // in_caps
#define KD  128   // in_dim
#define NC  32    // num_caps
#define DC  32    // dim_caps
#define CHUNK 64  // in_caps per block
#define NCH   8   // IC / CHUNK
#define NBLK  512 // Bsz * NCH
#define NTHR  256

#define CSTR 36   // padded stride for c_sT / wv_sT rows (floats)
#define BSTR 68   // padded stride for bb_s rows
#define WSTR 33   // padded stride for w_s rows: bank=(k+d)%32 -> conflict-free col+row reads

// workspace layout (floats)
#define CXP_SZ (Bsz * NCH * NC * KD)   // 8 MB   cx partials [b][ch][n][k]
#define WV_SZ  (Bsz * NC * KD)         // 1 MB   wv [b][n][k]

// x_s storage: row i holds k-quads rotated by (i>>2): quad' = (quad + (i>>2)) & 31
__device__ __forceinline__ int xaddr(int i, int kq) {
    return i * KD + ((((kq) + (i >> 2)) & 31) << 2);
}

// ---------------- Kernel A: [uv + bb update] + softmax + cx partials ----------------
// Byte-identical to r3 (verified 128.0us) EXCEPT x staging now uses
// global_load_lds width=16: LDS dest is lane-linear (slot = v), and the
// layout rotation is applied to the per-lane GLOBAL source index instead
// (same 512B row -> still fully coalesced). Content of x_s is bit-identical.
__global__ __launch_bounds__(NTHR)
void kA(const float* __restrict__ bb_in, const float* __restrict__ x_g,
        const float* __restrict__ wv_g, float* __restrict__ bb_out,
        float* __restrict__ cxp, int do_uv, int write_bb)
{
    __shared__ float x_s[CHUNK * KD];      // 32 KB, quad-rotated
    __shared__ float bb_s[NC * BSTR];      // 8.5 KB
    __shared__ float scr[KD * CSTR];       // 18 KB union: wv_sT [k][n] then c_sT [i][n]

    const int t = threadIdx.x, blk = blockIdx.x;
    const int b = blk >> 3, ch = blk & 7, i0g = ch * CHUNK;

    // stage x (rotated) via async global->LDS, 16B/lane
    for (int rep = 0; rep < 8; ++rep) {
        int v = t + rep * NTHR;            // float4 slot 0..2047 (lane-linear per wave)
        int i = v >> 5, kqs = v & 31;
        int kqr = (kqs - (i >> 2)) & 31;   // inverse rotation on the global side
        const float* gsrc = x_g + ((size_t)(b * IC + i0g + i)) * KD + (kqr << 2);
        __builtin_amdgcn_global_load_lds(
            (const __attribute__((address_space(1))) void*)gsrc,
            (__attribute__((address_space(3))) void*)(x_s + ((size_t)v << 2)),
            16, 0, 0);
    }
    // stage bb
    for (int rep = 0; rep < 2; ++rep) {
        int v = t + rep * NTHR;            // 0..511
        int n = v >> 4, i4 = v & 15;
        *(float4*)(bb_s + n * BSTR + (i4 << 2)) =
            *(const float4*)(bb_in + ((size_t)(b * NC + n)) * IC + i0g + (i4 << 2));
    }
    if (do_uv) {
        // stage wv transposed: [k][n] with CSTR pad
        for (int rep = 0; rep < 4; ++rep) {
            const int n = t & 31;
            const int k4 = (t >> 5) + (rep << 3);   // 0..31
            float4 v4 = *(const float4*)(wv_g + ((size_t)(b * NC) + n) * KD + (k4 << 2));
            scr[(k4 * 4 + 0) * CSTR + n] = v4.x;
            scr[(k4 * 4 + 1) * CSTR + n] = v4.y;
            scr[(k4 * 4 + 2) * CSTR + n] = v4.z;
            scr[(k4 * 4 + 3) * CSTR + n] = v4.w;
        }
    }
    __syncthreads();   // drains vmcnt (incl. global_load_lds) + lgkmcnt

    if (do_uv) {
        // uv = wv @ X^T ; bb += uv   (t<128: 4n x 4i tile each; r0/r3-proven)
        if (t < 128) {
            const int tn = t & 7, ti = t >> 3;
            const int n0 = tn << 2, i0 = ti << 2;
            float4 a0 = {0,0,0,0}, a1 = {0,0,0,0}, a2 = {0,0,0,0}, a3 = {0,0,0,0};
            for (int kq = 0; kq < 32; ++kq) {
                const float4 xr0 = *(const float4*)(x_s + xaddr(i0 + 0, kq));
                const float4 xr1 = *(const float4*)(x_s + xaddr(i0 + 1, kq));
                const float4 xr2 = *(const float4*)(x_s + xaddr(i0 + 2, kq));
                const float4 xr3 = *(const float4*)(x_s + xaddr(i0 + 3, kq));
                const float4 w0 = *(const float4*)(scr + (kq * 4 + 0) * CSTR + n0);
                const float4 w1 = *(const float4*)(scr + (kq * 4 + 1) * CSTR + n0);
                const float4 w2 = *(const float4*)(scr + (kq * 4 + 2) * CSTR + n0);
                const float4 w3 = *(const float4*)(scr + (kq * 4 + 3) * CSTR + n0);
                a0.x += xr0.x*w0.x + xr0.y*w1.x + xr0.z*w2.x + xr0.w*w3.x;
                a0.y += xr0.x*w0.y + xr0.y*w1.y + xr0.z*w2.y + xr0.w*w3.y;
                a0.z += xr0.x*w0.z + xr0.y*w1.z + xr0.z*w2.z + xr0.w*w3.z;
                a0.w += xr0.x*w0.w + xr0.y*w1.w + xr0.z*w2.w + xr0.w*w3.w;
                a1.x += xr1.x*w0.x + xr1.y*w1.x + xr1.z*w2.x + xr1.w*w3.x;
                a1.y += xr1.x*w0.y + xr1.y*w1.y + xr1.z*w2.y + xr1.w*w3.y;
                a1.z += xr1.x*w0.z + xr1.y*w1.z + xr1.z*w2.z + xr1.w*w3.z;
                a1.w += xr1.x*w0.w + xr1.y*w1.w + xr1.z*w2.w + xr1.w*w3.w;
                a2.x += xr2.x*w0.x + xr2.y*w1.x + xr2.z*w2.x + xr2.w*w3.x;
                a2.y += xr2.x*w0.y + xr2.y*w1.y + xr2.z*w2.y + xr2.w*w3.y;
                a2.z += xr2.x*w0.z + xr2.y*w1.z + xr2.z*w2.z + xr2.w*w3.z;
                a2.w += xr2.x*w0.w + xr2.y*w1.w + xr2.z*w2.w + xr2.w*w3.w;
                a3.x += xr3.x*w0.x + xr3.y*w1.x + xr3.z*w2.x + xr3.w*w3.x;
                a3.y += xr3.x*w0.y + xr3.y*w1.y + xr3.z*w2.y + xr3.w*w3.y;
                a3.z += xr3.x*w0.z + xr3.y*w1.z + xr3.z*w2.z + xr3.w*w3.z;
                a3.w += xr3.x*w0.w + xr3.y*w1.w + xr3.z*w2.w + xr3.w*w3.w;
            }
            bb_s[(n0+0)*BSTR + i0+0] += a0.x; bb_s[(n0+1)*BSTR + i0+0] += a0.y;
            bb_s[(n0+2)*BSTR + i0+0] += a0.z; bb_s[(n0+3)*BSTR + i0+0] += a0.w;
            bb_s[(n0+0)*BSTR + i0+1] += a1.x; bb_s[(n0+1)*BSTR + i0+1] += a1.y;
            bb_s[(n0+2)*BSTR + i0+1] += a1.z; bb_s[(n0+3)*BSTR + i0+1] += a1.w;
            bb_s[(n0+0)*BSTR + i0+2] += a2.x; bb_s[(n0+1)*BSTR + i0+2] += a2.y;
            bb_s[(n0+2)*BSTR + i0+2] += a2.z; bb_s[(n0+3)*BSTR + i0+2] += a2.w;
            bb_s[(n0+0)*BSTR + i0+3] += a3.x; bb_s[(n0+1)*BSTR + i0+3] += a3.y;
            bb_s[(n0+2)*BSTR + i0+3] += a3.z; bb_s[(n0+3)*BSTR + i0+3] += a3.w;
        }
        __syncthreads();
        if (write_bb) {
            for (int rep = 0; rep < 2; ++rep) {
                int v = t + rep * NTHR;
                int n = v >> 4, i4 = v & 15;
                *(float4*)(bb_out + ((size_t)(b * NC + n)) * IC + i0g + (i4 << 2)) =
                    *(const float4*)(bb_s + n * BSTR + (i4 << 2));
            }
        }
    }

    // softmax over n for each ii; write c^T into scr (r0/r3-proven serial form)
    if (t < CHUNK) {
        const int ii = t;
        float m = -1e30f;
        #pragma unroll
        for (int n = 0; n < NC; ++n) m = fmaxf(m, bb_s[n * BSTR + ii]);
        float e[NC]; float sum = 0.f;
        #pragma unroll
        for (int n = 0; n < NC; ++n) { float ev = __expf(bb_s[n * BSTR + ii] - m); e[n] = ev; sum += ev; }
        const float inv = 1.f / sum;
        float* crow = scr + ii * CSTR;
        #pragma unroll
        for (int n = 0; n < NC; ++n) crow[n] = e[n] * inv;
    }
    __syncthreads();

    // cx = C @ X (32n x 128k over 64 i); each thread 4n x 4k (r0/r3-proven)
    {
        const int tn = t & 7, tk = t >> 3;
        const int n0 = tn << 2;
        float4 acc0 = {0,0,0,0}, acc1 = {0,0,0,0}, acc2 = {0,0,0,0}, acc3 = {0,0,0,0};
        for (int ii = 0; ii < CHUNK; ++ii) {
            const float4 c4 = *(const float4*)(scr + ii * CSTR + n0);
            const float4 x4 = *(const float4*)(x_s + xaddr(ii, tk));
            acc0.x += c4.x*x4.x; acc0.y += c4.x*x4.y; acc0.z += c4.x*x4.z; acc0.w += c4.x*x4.w;
            acc1.x += c4.y*x4.x; acc1.y += c4.y*x4.y; acc1.z += c4.y*x4.z; acc1.w += c4.y*x4.w;
            acc2.x += c4.z*x4.x; acc2.y += c4.z*x4.y; acc2.z += c4.z*x4.z; acc2.w += c4.z*x4.w;
            acc3.x += c4.w*x4.x; acc3.y += c4.w*x4.y; acc3.z += c4.w*x4.z; acc3.w += c4.w*x4.w;
        }
        float* base = cxp + ((size_t)(b * NCH + ch)) * NC * KD + (tk << 2);
        *(float4*)(base + (size_t)(n0 + 0) * KD) = acc0;
        *(float4*)(base + (size_t)(n0 + 1) * KD) = acc1;
        *(float4*)(base + (size_t)(n0 + 2) * KD) = acc2;
        *(float4*)(base + (size_t)(n0 + 3) * KD) = acc3;
    }
}

// ---------------- Kernel B: reduce partials, s = cx@W[n], squash, wv or out ----------------
// (r3 structure, verified)
__global__ __launch_bounds__(NTHR)
void kB(const float* __restrict__ cxp, const float* __restrict__ W_g,
        float* __restrict__ wv_g, float* __restrict__ out_g, int final_)
{
    __shared__ float w_s[KD * WSTR];       // 16.5 KB, padded [k][d], bank=(k+d)%32
    __shared__ float cxs[4 * KD];          // 2 KB: per-wave reduced cx row
    __shared__ float vb[4 * DC];           // 512 B: per-wave squashed v

    const int t = threadIdx.x, blk = blockIdx.x;
    const int pb_n = blk & 31, pb_b0 = (blk >> 5) * 4;
    const int w = t >> 6, l = t & 63;
    const int b = pb_b0 + w;

    for (int rep = 0; rep < 4; ++rep) {
        int v = t + rep * NTHR;            // 0..1023 float4s
        int k = v >> 3, d0 = (v & 7) << 2;
        float4 w4 = *(const float4*)(W_g + (size_t)pb_n * KD * DC + ((size_t)v << 2));
        float* dst = w_s + k * WSTR + d0;
        dst[0] = w4.x; dst[1] = w4.y; dst[2] = w4.z; dst[3] = w4.w;
    }
    {
        float c0 = 0.f, c1 = 0.f;
        const float* p = cxp + ((size_t)b * NCH * NC + pb_n) * KD;
        #pragma unroll
        for (int c2 = 0; c2 < NCH; ++c2) {
            c0 += p[(size_t)c2 * NC * KD + l];
            c1 += p[(size_t)c2 * NC * KD + l + 64];
        }
        cxs[w * KD + l] = c0; cxs[w * KD + l + 64] = c1;
    }
    __syncthreads();

    const int dgrp = l & 7, d0 = dgrp << 2, kg = l >> 3;
    const float* cxw = cxs + w * KD;
    float4 acc = {0,0,0,0};
    #pragma unroll
    for (int j = 0; j < 16; ++j) {
        const int k = (j << 3) + kg;
        const float* wr = w_s + k * WSTR + d0;
        const float cv = cxw[k];
        acc.x += cv * wr[0]; acc.y += cv * wr[1]; acc.z += cv * wr[2]; acc.w += cv * wr[3];
    }
    #pragma unroll
    for (int off = 8; off < 64; off <<= 1) {
        acc.x += __shfl_xor(acc.x, off, 64);
        acc.y += __shfl_xor(acc.y, off, 64);
        acc.z += __shfl_xor(acc.z, off, 64);
        acc.w += __shfl_xor(acc.w, off, 64);
    }
    float ss = acc.x*acc.x + acc.y*acc.y + acc.z*acc.z + acc.w*acc.w;
    #pragma unroll
    for (int off = 1; off < 8; off <<= 1) ss += __shfl_xor(ss, off, 64);
    const float scale = ss / ((1.f + ss) * (sqrtf(ss) + 1e-8f));
    float4 v4; v4.x = acc.x*scale; v4.y = acc.y*scale; v4.z = acc.z*scale; v4.w = acc.w*scale;

    if (final_) {
        if (kg == 0) *(float4*)(out_g + ((size_t)(b * NC) + pb_n) * DC + d0) = v4;
    } else {
        float* vbw = vb + w * DC;
        if (kg == 0) *(float4*)(vbw + d0) = v4;
        __syncthreads();
        float wv0 = 0.f, wv1 = 0.f;
        #pragma unroll
        for (int j = 0; j < 8; ++j) {
            const float4 vv = *(const float4*)(vbw + (j << 2));
            const float* wa = w_s + l * WSTR + (j << 2);
            const float* wb = w_s + (l + 64) * WSTR + (j << 2);
            wv0 += wa[0]*vv.x + wa[1]*vv.y + wa[2]*vv.z + wa[3]*vv.w;
            wv1 += wb[0]*vv.x + wb[1]*vv.y + wb[2]*vv.z + wb[3]*vv.w;
        }
        float* wrow = wv_g + ((size_t)(b * NC) + pb_n) * KD;
        wrow[l] = wv0; wrow[l + 64] = wv1;
    }
}

extern "C" void kernel_launch(void* const* d_in, const int* in_sizes, int n_in,
                              void* d_out, int out_size, void* d_ws, size_t ws_size,
                              hipStream_t stream) {
    const float* x  = (const float*)d_in[0];
    const float* W  = (const float*)d_in[1];
    const float* b0 = (const float*)d_in[2];
    float* out = (float*)d_out;

    float* cxp   = (float*)d_ws;                 // 8 MB
    float* wv    = cxp + CXP_SZ;                 // 1 MB
    float* bb_ws = wv + WV_SZ;                   // 4 MB

    // iter 0: softmax(b0) + cx
    kA<<<NBLK, NTHR, 0, stream>>>(b0, x, nullptr, nullptr, cxp, 0, 0);
    kB<<<NBLK, NTHR, 0, stream>>>(cxp, W, wv, nullptr, 0);
    // iter 1: uv+bb (persist) + softmax + cx
    kA<<<NBLK, NTHR, 0, stream>>>(b0, x, wv, bb_ws, cxp, 1, 1);
    kB<<<NBLK, NTHR, 0, stream>>>(cxp, W, wv, nullptr, 0);
    // iter 2: uv+bb + softmax + cx (bb not persisted)
    kA<<<NBLK, NTHR, 0, stream>>>(bb_ws, x, wv, nullptr, cxp, 1, 0);
    kB<<<NBLK, NTHR, 0, stream>>>(cxp, W, nullptr, out, 1);
}